// Round 1
// baseline (344.614 us; speedup 1.0000x reference)
//
#include <hip/hip_runtime.h>
#include <math.h>

#define N_CVS   4096
#define FEAT    128
#define BATCH   8192
#define KNN_K   15
#define E_MIN_F 0.34867844f

typedef __attribute__((ext_vector_type(8))) short bf16x8;
typedef __attribute__((ext_vector_type(4))) float f32x4;
typedef __attribute__((ext_vector_type(4))) unsigned int u32x4;
typedef unsigned long long ull;

// ------- fused fp32->bf16 (RNE) + row norms (16 threads/row, shfl reduce) ---
__global__ void cvtnorm_kernel(const float* __restrict__ x, const float* __restrict__ cvs,
                               unsigned short* __restrict__ xb, unsigned short* __restrict__ cb,
                               float* __restrict__ x2, float* __restrict__ c2) {
    size_t tid = (size_t)blockIdx.x * 256 + threadIdx.x;
    size_t f = tid * 8;
    const float* src; unsigned short* dst; float* ndst; size_t row;
    if (f < (size_t)BATCH * FEAT) { src = x + f; dst = xb + f; row = f >> 7; ndst = x2 + row; }
    else {
        size_t g = f - (size_t)BATCH * FEAT;
        src = cvs + g; dst = cb + g; row = g >> 7; ndst = c2 + row;
    }
    float4 v0 = ((const float4*)src)[0];
    float4 v1 = ((const float4*)src)[1];
    float vv[8] = {v0.x, v0.y, v0.z, v0.w, v1.x, v1.y, v1.z, v1.w};
    bf16x8 o;
    float s = 0.f;
    #pragma unroll
    for (int i = 0; i < 8; ++i) {
        unsigned u = __float_as_uint(vv[i]);
        o[i] = (short)((u + 0x7fffu + ((u >> 16) & 1u)) >> 16);   // RNE
        s += vv[i] * vv[i];
    }
    *(bf16x8*)dst = o;
    #pragma unroll
    for (int off = 1; off < 16; off <<= 1) s += __shfl_xor(s, off, 64);
    if ((threadIdx.x & 15) == 0) *ndst = s;
}

// ---- fused GEMM + exact top-15 + scatter: d2 is NEVER materialized ---------
// 256 blocks x 512 threads: block owns 32 x-rows, sweeps all 4096 cvs in 32
// col-tiles (B dbuf in LDS, L2-resident 1MB bf16). Per tile each lane builds
// (f32bits<<32)|col keys from its MFMA acc and appends candidates beating the
// row's current 15th key into a per-row LDS buffer; wave-0 lanes keep the
// sorted-15 lists in REGISTERS (rule #20: all indices compile-time). Capped
// buffer + overflow retry keeps it exact (identical MFMA chain order to the
// previous mfma_d2 kernel -> bit-identical selection vs the passing version).
#define LROW  272
#define BROWS 32
#define CAP   64
#define NTILE (N_CVS / 128)

__global__ __launch_bounds__(512, 2) void mfma_topk_kernel(
        const unsigned short* __restrict__ xb, const unsigned short* __restrict__ cb,
        const float* __restrict__ x2g, const float* __restrict__ c2g,
        int* __restrict__ visits, unsigned int* __restrict__ cce8) {
    __shared__ __align__(16) char Bl[2][128 * LROW];   // 68 KB
    __shared__ __align__(16) char Al[BROWS * LROW];    // 8.5 KB
    __shared__ ull cand[BROWS][CAP];                   // 16 KB
    __shared__ ull kT[BROWS];
    __shared__ int cnt[BROWS];
    __shared__ int ofl[BROWS];

    const int t  = threadIdx.x;
    const int bi = blockIdx.x * BROWS;

    // stage A once (32 rows x 128 K bf16), 1 x 16B chunk per thread
    {
        int row = t >> 4, g = t & 15;
        *(ulonglong2*)(Al + row * LROW + g * 16) =
            *(const ulonglong2*)((const char*)(xb + (size_t)(bi + row) * FEAT) + g * 16);
    }
    // stage B tile 0
    #pragma unroll
    for (int i = 0; i < 4; ++i) {
        int f = t + i * 512, row = f >> 4, g = f & 15;
        *(ulonglong2*)(Bl[0] + row * LROW + g * 16) =
            *(const ulonglong2*)((const char*)(cb + (size_t)row * FEAT) + g * 16);
    }
    if (t < BROWS) { cnt[t] = 0; kT[t] = ~0ULL; ofl[t] = 0; }
    __syncthreads();

    const int lane = t & 63;
    const int w    = t >> 6;             // 8 waves = 8 col strips of 16
    const int l15  = lane & 15, quad = lane >> 4;

    bf16x8 a[2][4];
    float  x2r[2][4];
    #pragma unroll
    for (int si = 0; si < 2; ++si) {
        #pragma unroll
        for (int ks = 0; ks < 4; ++ks)
            a[si][ks] = *(const bf16x8*)(Al + (si * 16 + l15) * LROW + ks * 64 + quad * 16);
        #pragma unroll
        for (int r = 0; r < 4; ++r)
            x2r[si][r] = x2g[bi + si * 16 + quad * 4 + r];
    }

    ull lst[15];                          // wave-0 lanes: sorted top-15 of row=lane
    #pragma unroll
    for (int i = 0; i < 15; ++i) lst[i] = ~0ULL;

    for (int tj = 0; tj < NTILE; ++tj) {
        const char* cur = Bl[tj & 1];
        if (tj + 1 < NTILE) {             // prefetch next B tile into other buf
            char* nxt = Bl[(tj + 1) & 1];
            const int cjn = (tj + 1) * 128;
            #pragma unroll
            for (int i = 0; i < 4; ++i) {
                int f = t + i * 512, row = f >> 4, g = f & 15;
                *(ulonglong2*)(nxt + row * LROW + g * 16) =
                    *(const ulonglong2*)((const char*)(cb + (size_t)(cjn + row) * FEAT) + g * 16);
            }
        }

        f32x4 acc[2] = {(f32x4){0.f,0.f,0.f,0.f}, (f32x4){0.f,0.f,0.f,0.f}};
        #pragma unroll
        for (int ks = 0; ks < 4; ++ks) {  // same ks chain order as old kernel
            bf16x8 b = *(const bf16x8*)(cur + (w * 16 + l15) * LROW + ks * 64 + quad * 16);
            acc[0] = __builtin_amdgcn_mfma_f32_16x16x32_bf16(a[0][ks], b, acc[0], 0, 0, 0);
            acc[1] = __builtin_amdgcn_mfma_f32_16x16x32_bf16(a[1][ks], b, acc[1], 0, 0, 0);
        }

        const int col = tj * 128 + w * 16 + l15;
        const float c2v = c2g[col];
        ull key[2][4];
        #pragma unroll
        for (int si = 0; si < 2; ++si)
            #pragma unroll
            for (int r = 0; r < 4; ++r) {
                float v = fmaxf(x2r[si][r] + c2v - 2.0f * acc[si][r], 0.0f);
                key[si][r] = ((ull)__float_as_uint(v) << 32) | (unsigned)col;
            }

        unsigned am = 0;                  // per-value "already appended" bits
        int round = 0, more;
        do {
            #pragma unroll
            for (int si = 0; si < 2; ++si)
                #pragma unroll
                for (int r = 0; r < 4; ++r) {
                    int rl = si * 16 + quad * 4 + r;
                    unsigned bit = 1u << (si * 4 + r);
                    if (!(am & bit) && (round == 0 || ofl[rl]) && key[si][r] < kT[rl]) {
                        int pos = atomicAdd(&cnt[rl], 1);
                        if (pos < CAP) { cand[rl][pos] = key[si][r]; am |= bit; }
                    }
                }
            __syncthreads();
            int of = 0;
            if (t < BROWS) {
                int n = cnt[t];
                if (n) {
                    int m = n < CAP ? n : CAP;
                    for (int i = 0; i < m; ++i) {
                        ull k = cand[t][i];
                        #pragma unroll
                        for (int q = 0; q < 15; ++q) {   // bubble-insert, keep 15 smallest
                            ull lo = k < lst[q] ? k : lst[q];
                            ull hi = k < lst[q] ? lst[q] : k;
                            lst[q] = lo; k = hi;
                        }
                    }
                    kT[t]  = lst[14];
                    cnt[t] = 0;
                    of = (n > CAP);
                }
                ofl[t] = of;
            }
            more = __syncthreads_or(of);
            ++round;
        } while (more);
    }

    // fused scatter: wave-0 lane r owns row r
    if (t < BROWS) {
        int closest = (int)(unsigned)(lst[0] & 0xffffffffu);
        atomicAdd(&visits[closest], 1);
        size_t cbase = (size_t)closest * N_CVS;
        #pragma unroll
        for (int k = 0; k < KNN_K; ++k) {
            size_t idx = cbase + (unsigned)(lst[k] & 0xffffffffu);
            atomicAdd((int*)&cce8[idx >> 2], 1 << ((idx & 3) * 8));
        }
    }
}

// ---------------- neighbor mask bits: one block per row, 16 elems/thread ----
// enc<=9 integer rule: np computes 0.9f**enc in fp32; 0.9f^10 < E_MIN, so
// enc==10 edges are dropped by the reference (verified absmax 0.0 in R8).
// conn loaded conditionally (~0.8% density).
__global__ __launch_bounds__(256) void bits_kernel(
        const unsigned int* __restrict__ cce8, const int* __restrict__ visits,
        const float* __restrict__ edges, const float* __restrict__ conn,
        unsigned short* __restrict__ bits16) {
    const int row = blockIdx.x;
    const int t   = threadIdx.x;
    const int vis = visits[row];
    size_t eb = (size_t)row * N_CVS + t * 16;
    f32x4 e[4];
    #pragma unroll
    for (int q = 0; q < 4; ++q) e[q] = ((const f32x4*)(edges + eb))[q];
    u32x4 cw = ((const u32x4*)(cce8 + (size_t)row * 1024))[t];

    unsigned pre = 0;
    #pragma unroll
    for (int q = 0; q < 4; ++q) {
        #pragma unroll
        for (int s = 0; s < 4; ++s) {
            int cc = (cw[q] >> (s * 8)) & 0xff;
            float ev = e[q][s];
            float ex = (cc > 0) ? fmaxf(ev, 1.0f) : ev;
            bool p;
            if (ex == 1.0f) {
                p = (vis - cc) <= 9;
            } else if (ex > 0.0f) {
                float enc = fmaxf((float)(vis - cc), 0.0f);
                p = ex * powf(0.9f, enc) >= E_MIN_F;
            } else {
                p = false;
            }
            pre |= (unsigned)p << (q * 4 + s);
        }
    }
    unsigned m = 0;
    #pragma unroll
    for (int q = 0; q < 4; ++q) {
        unsigned pn = (pre >> (q * 4)) & 0xfu;
        if (pn) {
            f32x4 cv = ((const f32x4*)(conn + eb))[q];
            #pragma unroll
            for (int s = 0; s < 4; ++s)
                if (((pn >> s) & 1u) && (cv[s] < 1.0f)) m |= 1u << (q * 4 + s);
        }
    }
    bits16[(size_t)row * 256 + t] = (unsigned short)m;
}

// ------- per-sample masked soft-min loss, d2 recomputed on the fly ----------
// One wave per sample: cooperative 128-dim dot per masked j (fp32 x / cvs,
// both L2-resident), butterfly reduce. ~31 dots/sample = 63 MFLOP total.
__global__ __launch_bounds__(256) void loss_kernel(
        const float* __restrict__ x, const float* __restrict__ cvs,
        const ull* __restrict__ bits, const int* __restrict__ labels,
        float* __restrict__ partial) {
    int wid  = blockIdx.x * 4 + (threadIdx.x >> 6);
    int lane = threadIdx.x & 63;
    int l = labels[wid];
    float2 xv = ((const float2*)(x + (size_t)wid * FEAT))[lane];
    ull myw = bits[(size_t)l * 64 + lane];

    float dpos;
    {
        float2 c = ((const float2*)(cvs + (size_t)l * FEAT))[lane];
        float d0 = xv.x - c.x, d1 = xv.y - c.y;
        float s = d0 * d0 + d1 * d1;
        #pragma unroll
        for (int off = 32; off > 0; off >>= 1) s += __shfl_xor(s, off, 64);
        dpos = s;
    }

    float se = 0.f, sed = 0.f;
    ull nz = __ballot(myw != 0ULL);
    while (nz) {
        int wd = __builtin_ctzll(nz);
        nz &= nz - 1;
        ull word = __shfl(myw, wd, 64);
        while (word) {
            int b = __builtin_ctzll(word);
            word &= word - 1;
            int j = wd * 64 + b;
            float2 c = ((const float2*)(cvs + (size_t)j * FEAT))[lane];
            float d0 = xv.x - c.x, d1 = xv.y - c.y;
            float s = d0 * d0 + d1 * d1;
            #pragma unroll
            for (int off = 32; off > 0; off >>= 1) s += __shfl_xor(s, off, 64);
            if (s > 0.f) {
                float ee = __expf(-0.001f * s);
                se += ee; sed += ee * s;
            }
        }
    }
    if (lane == 0) {
        float wsum = se > 0.f ? sed / se : 0.f;
        float mu = dpos - wsum;
        partial[wid] = (mu > 0.f) ? mu : 0.f;
    }
}

// ---------------- final reduction: sum(partial)/BATCH -> out ----------------
__global__ void reduce_kernel(const float* __restrict__ partial, float* __restrict__ out) {
    int t = threadIdx.x;
    float s = 0.f;
    #pragma unroll
    for (int i = 0; i < BATCH / 256; ++i) s += partial[t + i * 256];
    #pragma unroll
    for (int off = 32; off > 0; off >>= 1) s += __shfl_xor(s, off, 64);
    __shared__ float wsum[4];
    if ((t & 63) == 0) wsum[t >> 6] = s;
    __syncthreads();
    if (t == 0) out[0] = (wsum[0] + wsum[1] + wsum[2] + wsum[3]) * (1.0f / BATCH);
}

extern "C" void kernel_launch(void* const* d_in, const int* in_sizes, int n_in,
                              void* d_out, int out_size, void* d_ws, size_t ws_size,
                              hipStream_t stream) {
    const float* x      = (const float*)d_in[0];
    const float* cvs    = (const float*)d_in[1];
    const float* edges  = (const float*)d_in[2];
    const float* conn   = (const float*)d_in[3];
    const int*   labels = (const int*)d_in[4];

    char* p = (char*)d_ws;
    int* visits = (int*)p;                  p += (size_t)N_CVS * 4;           // 16 KB
    unsigned int* cce8 = (unsigned int*)p;  p += (size_t)N_CVS * N_CVS;       // 16 MB (u8)
    ull* bits = (ull*)p;                    p += (size_t)N_CVS * 64 * 8;      // 2 MB
    float* x2 = (float*)p;                  p += (size_t)BATCH * 4;
    float* c2 = (float*)p;                  p += (size_t)N_CVS * 4;
    unsigned short* xb = (unsigned short*)p; p += (size_t)BATCH * FEAT * 2;   // 2 MB
    unsigned short* cb = (unsigned short*)p; p += (size_t)N_CVS * FEAT * 2;   // 1 MB
    float* partial = (float*)p;             p += (size_t)BATCH * 4;           // 32 KB

    // zero visits + cce8 (contiguous)
    hipMemsetAsync(visits, 0, (size_t)N_CVS * 4 + (size_t)N_CVS * N_CVS, stream);

    cvtnorm_kernel  <<<(BATCH + N_CVS) * FEAT / 8 / 256, 256, 0, stream>>>(x, cvs, xb, cb, x2, c2);
    mfma_topk_kernel<<<BATCH / BROWS, 512, 0, stream>>>(xb, cb, x2, c2, visits, cce8);
    bits_kernel     <<<N_CVS, 256, 0, stream>>>(cce8, visits, edges, conn, (unsigned short*)bits);
    loss_kernel     <<<BATCH / 4, 256, 0, stream>>>(x, cvs, bits, labels, partial);
    reduce_kernel   <<<1, 256, 0, stream>>>(partial, (float*)d_out);
}